// Round 4
// baseline (121.541 us; speedup 1.0000x reference)
//
#include <hip/hip_runtime.h>

#define B_   4
#define Q_   256
#define C_   1024
#define H_   128

// ---------------------------------------------------------------------------
// Kernel 1: hq[b,q,k]   = sum_h query[b,q,h]*Ww[k,h]
//           hcT[b,k,c]  = sum_h context[b,c,h]*Ww[k,H+h] + bw[k]   (TRANSPOSED)
//           dcv[b,c]    = 0.505 * sum_k Ws[k]*hc[b,c,k]
// 8 rows per block, 256 threads: k = t&127, half = t>>7 owns 4 rows.
// Both halves read the same Ww rows -> L1 temporal reuse halves W L2 traffic.
// hcT store is one float4 per thread (contiguous in c).
// ---------------------------------------------------------------------------
__global__ __launch_bounds__(256) void proj_kernel(
    const float* __restrict__ query, const float* __restrict__ context,
    const float* __restrict__ Ww, const float* __restrict__ bw,
    const float* __restrict__ Ws,
    float* __restrict__ hq, float* __restrict__ hcT, float* __restrict__ dcv)
{
    __shared__ float dpar[2][2][4];

    const int blk  = blockIdx.x;
    const int t    = threadIdx.x;
    const int k    = t & 127;
    const int half = t >> 7;
    const bool is_q = (blk < (B_ * Q_ / 8));          // 128 q-blocks, 512 c-blocks
    const int row0 = (is_q ? blk * 8 : (blk - B_ * Q_ / 8) * 8) + half * 4;
    const float* __restrict__ in = is_q ? query : context;

    const float4* __restrict__ Wrow =
        reinterpret_cast<const float4*>(Ww + k * (2 * H_) + (is_q ? 0 : H_));
    const float4* __restrict__ in4 =
        reinterpret_cast<const float4*>(in + row0 * H_);

    float acc[4] = {0.f, 0.f, 0.f, 0.f};
    #pragma unroll 4
    for (int h4 = 0; h4 < H_ / 4; ++h4) {
        const float4 w = Wrow[h4];
        #pragma unroll
        for (int r = 0; r < 4; ++r) {
            const float4 iv = in4[r * (H_ / 4) + h4];     // wave-uniform
            acc[r] += iv.x * w.x + iv.y * w.y + iv.z * w.z + iv.w * w.w;
        }
    }

    if (is_q) {
        #pragma unroll
        for (int r = 0; r < 4; ++r)
            hq[(row0 + r) * H_ + k] = acc[r];
    } else {
        const float bias = bw[k];
        #pragma unroll
        for (int r = 0; r < 4; ++r) acc[r] += bias;

        // transposed store: hcT[b][k][c] (c contiguous per thread)
        const int b  = row0 >> 10;                     // c-row index / C_
        const int cl = row0 & (C_ - 1);
        *reinterpret_cast<float4*>(hcT + (b * H_ + k) * C_ + cl) =
            make_float4(acc[0], acc[1], acc[2], acc[3]);

        // dcv: cross-thread reduce over k (2 waves per half)
        const float wsk = Ws[k];
        float p[4];
        #pragma unroll
        for (int r = 0; r < 4; ++r) p[r] = wsk * acc[r];
        #pragma unroll
        for (int off = 32; off >= 1; off >>= 1) {
            #pragma unroll
            for (int r = 0; r < 4; ++r) p[r] += __shfl_xor(p[r], off, 64);
        }
        if ((k & 63) == 0) {
            #pragma unroll
            for (int r = 0; r < 4; ++r) dpar[half][k >> 6][r] = p[r];
        }
        __syncthreads();                               // block-uniform branch
        if (t < 8) {
            const int hh = t >> 2, r = t & 3;
            const int crow = (blk - B_ * Q_ / 8) * 8 + hh * 4 + r;
            dcv[(crow >> 10) * C_ + (crow & (C_ - 1))] =
                0.505f * (dpar[hh][0][r] + dpar[hh][1][r]);
        }
    }
}

// ---------------------------------------------------------------------------
// Kernel 2: per block = (b, 4 consecutive q). 512 threads (8 waves).
// b = blockIdx & 3 pins each XCD to one b (hcT[b]+context[b] L2-local).
// score[q,c] = 0.505*dc[c] + sum_k (0.495*Ws[k])*|hq+hc|   (exact identity;
// Dq[q] and bs are c-constant -> softmax-shift-invariant -> dropped).
// Phase-1 hc reads are COALESCED via the hcT[b][k][c] layout: thread owns
// c-pair {2t, 2t+1}, float2 load = 512 B/wave (8 lines vs 64 uncoalesced).
// ---------------------------------------------------------------------------
__global__ __launch_bounds__(512) void attn_kernel(
    const float* __restrict__ hq, const float* __restrict__ hcT,
    const float* __restrict__ Ws, const float* __restrict__ dcv,
    const float* __restrict__ context,
    float* __restrict__ outA, float* __restrict__ outP)
{
    const int b  = blockIdx.x & 3;           // XCD-aligned b mapping
    const int q0 = (blockIdx.x >> 2) * 4;    // 64 q-groups per b
    const int t  = threadIdx.x;
    const int wv = t >> 6;                   // wave id 0..7

    __shared__ float4 attn4_s[C_];                      // 16 KiB
    __shared__ float  red[16 * 4 * H_];                 // 32 KiB
    __shared__ __align__(16) float s_hq[4][H_];         // 2 KiB
    __shared__ __align__(16) float s_ws[H_];            // 0.5 KiB
    __shared__ float  wred[8][4];
    __shared__ float  wsum[8][4];

    // phase-3 context prefetch (addresses known at entry; loads retire
    // under phase 1/2 — occupancy is grid-limited so +32 VGPRs is free)
    const float4* __restrict__ ctx4 = reinterpret_cast<const float4*>(context);
    const int hg   = t & 31;
    const int crep = t >> 5;
    const int cb   = crep * 64;
    float4 pf[8];
    #pragma unroll
    for (int i = 0; i < 8; ++i)
        pf[i] = ctx4[(b * C_ + cb + i) * (H_ / 4) + hg];

    // stage hq rows + pre-scaled Ws into LDS; read linear term
    {
        const int q = t >> 7, kk = t & 127;
        s_hq[q][kk] = hq[(b * Q_ + q0 + q) * H_ + kk];
        if (t < H_) s_ws[t] = 0.495f * Ws[t];
    }
    const int c0 = 2 * t;                    // thread owns {2t, 2t+1}
    const float dc0 = dcv[b * C_ + c0];
    const float dc1 = dcv[b * C_ + c0 + 1];
    __syncthreads();

    // ---- phase 1: abs-part over the c-pair, k = 0..127 coalesced over c
    const float4* __restrict__ ws4 = reinterpret_cast<const float4*>(s_ws);
    const float2* __restrict__ hcT2 =
        reinterpret_cast<const float2*>(hcT + b * H_ * C_);

    float sabs[4][2] = {{0.f,0.f},{0.f,0.f},{0.f,0.f},{0.f,0.f}};
    #pragma unroll 4
    for (int k4 = 0; k4 < H_ / 4; ++k4) {
        const float4 wsv = ws4[k4];                        // LDS broadcast
        float wk[4]  = {wsv.x, wsv.y, wsv.z, wsv.w};
        float hqk[4][4];
        #pragma unroll
        for (int q = 0; q < 4; ++q) {
            const float4 hv = reinterpret_cast<const float4*>(s_hq[q])[k4];
            hqk[q][0] = hv.x; hqk[q][1] = hv.y; hqk[q][2] = hv.z; hqk[q][3] = hv.w;
        }
        #pragma unroll
        for (int kk = 0; kk < 4; ++kk) {
            const float2 hv = hcT2[(k4 * 4 + kk) * (C_ / 2) + t];  // coalesced
            #pragma unroll
            for (int q = 0; q < 4; ++q) {
                sabs[q][0] += wk[kk] * fabsf(hqk[q][kk] + hv.x);
                sabs[q][1] += wk[kk] * fabsf(hqk[q][kk] + hv.y);
            }
        }
    }
    float s[4][2];
    #pragma unroll
    for (int q = 0; q < 4; ++q) {
        s[q][0] = dc0 + sabs[q][0];
        s[q][1] = dc1 + sabs[q][1];
    }

    // ---- phase 2: softmax over the 1024 c per q row
    float m[4];
    #pragma unroll
    for (int q = 0; q < 4; ++q) {
        float v = fmaxf(s[q][0], s[q][1]);
        #pragma unroll
        for (int off = 32; off >= 1; off >>= 1)
            v = fmaxf(v, __shfl_xor(v, off, 64));
        m[q] = v;
    }
    if ((t & 63) == 0) {
        #pragma unroll
        for (int q = 0; q < 4; ++q) wred[wv][q] = m[q];
    }
    __syncthreads();
    #pragma unroll
    for (int q = 0; q < 4; ++q) {
        float v = wred[0][q];
        #pragma unroll
        for (int i = 1; i < 8; ++i) v = fmaxf(v, wred[i][q]);
        m[q] = v;
    }
    float e[4][2], p[4];
    #pragma unroll
    for (int q = 0; q < 4; ++q) {
        e[q][0] = __expf(s[q][0] - m[q]);
        e[q][1] = __expf(s[q][1] - m[q]);
        float v = e[q][0] + e[q][1];
        #pragma unroll
        for (int off = 32; off >= 1; off >>= 1)
            v += __shfl_xor(v, off, 64);
        p[q] = v;
    }
    if ((t & 63) == 0) {
        #pragma unroll
        for (int q = 0; q < 4; ++q) wsum[wv][q] = p[q];
    }
    __syncthreads();
    float rS[4];
    #pragma unroll
    for (int q = 0; q < 4; ++q) {
        float S = wsum[0][q];
        #pragma unroll
        for (int i = 1; i < 8; ++i) S += wsum[i][q];
        rS[q] = 1.0f / S;
    }
    float a0[4], a1[4];
    #pragma unroll
    for (int q = 0; q < 4; ++q) {
        a0[q] = e[q][0] * rS[q];
        a1[q] = e[q][1] * rS[q];
    }
    attn4_s[c0]     = make_float4(a0[0], a0[1], a0[2], a0[3]);
    attn4_s[c0 + 1] = make_float4(a1[0], a1[1], a1[2], a1[3]);
    #pragma unroll
    for (int q = 0; q < 4; ++q) {
        *reinterpret_cast<float2*>(outP + (b * Q_ + q0 + q) * C_ + c0) =
            make_float2(a0[q], a1[q]);                  // coalesced 512 B/wave
    }
    __syncthreads();

    // ---- phase 3: attn_output[q][h] = sum_c attn[q][c]*context[b][c][h]
    float4 acc[4] = {{0,0,0,0},{0,0,0,0},{0,0,0,0},{0,0,0,0}};
    #pragma unroll
    for (int cc = 0; cc < 8; ++cc) {                    // prefetched head
        const float4 a4 = attn4_s[cb + cc];
        const float4 xv = pf[cc];
        acc[0].x += a4.x * xv.x; acc[0].y += a4.x * xv.y; acc[0].z += a4.x * xv.z; acc[0].w += a4.x * xv.w;
        acc[1].x += a4.y * xv.x; acc[1].y += a4.y * xv.y; acc[1].z += a4.y * xv.z; acc[1].w += a4.y * xv.w;
        acc[2].x += a4.z * xv.x; acc[2].y += a4.z * xv.y; acc[2].z += a4.z * xv.z; acc[2].w += a4.z * xv.w;
        acc[3].x += a4.w * xv.x; acc[3].y += a4.w * xv.y; acc[3].z += a4.w * xv.z; acc[3].w += a4.w * xv.w;
    }
    #pragma unroll 4
    for (int cc = 8; cc < 64; ++cc) {
        const int c = cb + cc;
        const float4 a4 = attn4_s[c];
        const float4 xv = ctx4[(b * C_ + c) * (H_ / 4) + hg];
        acc[0].x += a4.x * xv.x; acc[0].y += a4.x * xv.y; acc[0].z += a4.x * xv.z; acc[0].w += a4.x * xv.w;
        acc[1].x += a4.y * xv.x; acc[1].y += a4.y * xv.y; acc[1].z += a4.y * xv.z; acc[1].w += a4.y * xv.w;
        acc[2].x += a4.z * xv.x; acc[2].y += a4.z * xv.y; acc[2].z += a4.z * xv.z; acc[2].w += a4.z * xv.w;
        acc[3].x += a4.w * xv.x; acc[3].y += a4.w * xv.y; acc[3].z += a4.w * xv.z; acc[3].w += a4.w * xv.w;
    }
    float4* red4 = reinterpret_cast<float4*>(red);
    #pragma unroll
    for (int q = 0; q < 4; ++q)
        red4[(crep * 4 + q) * 32 + hg] = acc[q];
    __syncthreads();
    {
        const int q = t >> 7, h = t & 127;
        float v = 0.f;
        #pragma unroll
        for (int cr = 0; cr < 16; ++cr)
            v += red[(cr * 4 + q) * H_ + h];
        outA[(b * Q_ + q0 + q) * H_ + h] = v;
    }
}

extern "C" void kernel_launch(void* const* d_in, const int* in_sizes, int n_in,
                              void* d_out, int out_size, void* d_ws, size_t ws_size,
                              hipStream_t stream) {
    const float* query   = (const float*)d_in[0];
    const float* context = (const float*)d_in[1];
    const float* Ww      = (const float*)d_in[2];
    const float* bw      = (const float*)d_in[3];
    const float* Ws      = (const float*)d_in[4];
    // d_in[5] (bs) unused: softmax-shift-invariant, outputs are post-softmax.

    float* outA = (float*)d_out;                 // attn_output: B*Q*H
    float* outP = outA + B_ * Q_ * H_;           // attn:        B*Q*C

    float* hq  = (float*)d_ws;                   // B*Q*H floats (512 KB)
    float* hcT = hq + B_ * Q_ * H_;              // B*H*C floats (2 MB, transposed)
    float* dcv = hcT + B_ * H_ * C_;             // B*C floats   (16 KB)

    hipLaunchKernelGGL(proj_kernel, dim3(640), dim3(256), 0, stream,
                       query, context, Ww, bw, Ws, hq, hcT, dcv);
    hipLaunchKernelGGL(attn_kernel, dim3(256), dim3(512), 0, stream,
                       hq, hcT, Ws, dcv, context, outA, outP);
}

// Round 5
// 104.450 us; speedup vs baseline: 1.1636x; 1.1636x over previous
//
#include <hip/hip_runtime.h>

#define B_   4
#define Q_   256
#define C_   1024
#define H_   128

// ---------------------------------------------------------------------------
// Kernel 1 (identical to the verified round-3 version):
//   hq[b,q,k]  = sum_h query[b,q,h]*Ww[k,h]
//   hc[b,c,k]  = sum_h context[b,c,h]*Ww[k,H+h] + bw[k]     (row-major)
//   dcv[b,c]   = sum_k Ws[k]*hc[b,c,k]                      (linear term)
// 4 rows per block, 128 threads (thread = output k) -> 1280 blocks.
// ---------------------------------------------------------------------------
__global__ __launch_bounds__(128) void proj_kernel(
    const float* __restrict__ query, const float* __restrict__ context,
    const float* __restrict__ Ww, const float* __restrict__ bw,
    const float* __restrict__ Ws,
    float* __restrict__ hq, float* __restrict__ hc, float* __restrict__ dcv)
{
    __shared__ float dpar[2][4];

    const int blk = blockIdx.x;
    const int k = threadIdx.x;
    const bool is_q = (blk < (B_ * Q_ / 4));              // 256 blocks for hq
    const int row0 = is_q ? (blk * 4) : ((blk - B_ * Q_ / 4) * 4);
    const float* __restrict__ in = is_q ? query : context;
    float* __restrict__ out = is_q ? hq : hc;

    const float4* __restrict__ Wrow =
        reinterpret_cast<const float4*>(Ww + k * (2 * H_) + (is_q ? 0 : H_));
    const float4* __restrict__ in4 =
        reinterpret_cast<const float4*>(in + row0 * H_);

    float acc[4] = {0.f, 0.f, 0.f, 0.f};
    #pragma unroll 4
    for (int h4 = 0; h4 < H_ / 4; ++h4) {
        const float4 w = Wrow[h4];
        #pragma unroll
        for (int r = 0; r < 4; ++r) {
            const float4 iv = in4[r * (H_ / 4) + h4];     // wave-uniform
            acc[r] += iv.x * w.x + iv.y * w.y + iv.z * w.z + iv.w * w.w;
        }
    }
    const float bias = is_q ? 0.f : bw[k];
    #pragma unroll
    for (int r = 0; r < 4; ++r) {
        acc[r] += bias;
        out[(row0 + r) * H_ + k] = acc[r];
    }

    if (!is_q) {                                          // block-uniform branch
        const float wsk = Ws[k];
        float p[4];
        #pragma unroll
        for (int r = 0; r < 4; ++r) p[r] = wsk * acc[r];
        #pragma unroll
        for (int off = 32; off >= 1; off >>= 1) {
            #pragma unroll
            for (int r = 0; r < 4; ++r) p[r] += __shfl_xor(p[r], off, 64);
        }
        if ((k & 63) == 0) {
            #pragma unroll
            for (int r = 0; r < 4; ++r) dpar[k >> 6][r] = p[r];
        }
        __syncthreads();
        if (k < 4) dcv[row0 + k] = dpar[0][k] + dpar[1][k];
    }
}

// ---------------------------------------------------------------------------
// Kernel 2: per block = (b, 4 consecutive q). 1024 threads (16 waves).
// Grid = 256 blocks = 1 block/CU, so block SIZE sets occupancy:
// 16 waves/CU = 4/SIMD (2x round-3's latency hiding). Thread owns ONE c.
// hc reads use the round-3 pattern (lane walks its own row in 16B steps,
// 75% L1 hit rate) — proven faster than the "coalesced" transposed layout.
// score[q,c] = 0.505*dc[c] + sum_k (0.495*Ws[k])*|hq+hc|  (exact identity;
// Dq[q] and bs are c-constant -> softmax-shift-invariant -> dropped).
// ---------------------------------------------------------------------------
__global__ __launch_bounds__(1024) void attn_kernel(
    const float* __restrict__ hq, const float* __restrict__ hc,
    const float* __restrict__ Ws, const float* __restrict__ dcv,
    const float* __restrict__ context,
    float* __restrict__ outA, float* __restrict__ outP)
{
    const int b  = blockIdx.x & 3;           // XCD-aligned b mapping
    const int q0 = (blockIdx.x >> 2) * 4;    // 64 q-groups per b
    const int t  = threadIdx.x;
    const int wv = t >> 6;                   // wave id 0..15

    __shared__ float4 attn4_s[C_];                      // 16 KiB
    __shared__ float  red[16 * 4 * H_];                 // 32 KiB
    __shared__ __align__(16) float s_hq[4][H_];         // 2 KiB
    __shared__ __align__(16) float s_ws[H_];            // 0.5 KiB
    __shared__ float  wred[16][4];
    __shared__ float  wsum[16][4];

    // stage hq rows + pre-scaled Ws into LDS; read linear term
    if (t < 512) {
        const int q = t >> 7, kk = t & 127;
        s_hq[q][kk] = hq[(b * Q_ + q0 + q) * H_ + kk];
    }
    if (t < H_) s_ws[t] = 0.495f * Ws[t];
    const float dc = dcv[b * C_ + t];        // thread owns c = t
    __syncthreads();

    // ---- phase 1: abs-part for c = t, k = 0..127 (per-lane row walk, L1-hot)
    const float4* __restrict__ ws4 = reinterpret_cast<const float4*>(s_ws);
    const float4* __restrict__ hcp =
        reinterpret_cast<const float4*>(hc + (b * C_ + t) * H_);

    float sabs[4] = {0.f, 0.f, 0.f, 0.f};
    #pragma unroll 4
    for (int k4 = 0; k4 < H_ / 4; ++k4) {
        const float4 wsv = ws4[k4];                        // LDS broadcast
        const float4 hv  = hcp[k4];                        // 16B per-lane
        #pragma unroll
        for (int q = 0; q < 4; ++q) {
            const float4 hqv = reinterpret_cast<const float4*>(s_hq[q])[k4];
            sabs[q] += wsv.x * fabsf(hqv.x + hv.x)
                     + wsv.y * fabsf(hqv.y + hv.y)
                     + wsv.z * fabsf(hqv.z + hv.z)
                     + wsv.w * fabsf(hqv.w + hv.w);
        }
    }
    float s[4];
    #pragma unroll
    for (int q = 0; q < 4; ++q) s[q] = fmaf(0.505f, dc, sabs[q]);

    // ---- phase 2: softmax over the 1024 c per q row (16 waves)
    float m[4];
    #pragma unroll
    for (int q = 0; q < 4; ++q) {
        float v = s[q];
        #pragma unroll
        for (int off = 32; off >= 1; off >>= 1)
            v = fmaxf(v, __shfl_xor(v, off, 64));
        m[q] = v;
    }
    if ((t & 63) == 0) {
        #pragma unroll
        for (int q = 0; q < 4; ++q) wred[wv][q] = m[q];
    }
    __syncthreads();
    #pragma unroll
    for (int q = 0; q < 4; ++q) {
        float v = wred[0][q];
        #pragma unroll
        for (int i = 1; i < 16; ++i) v = fmaxf(v, wred[i][q]);
        m[q] = v;
    }
    float e[4];
    #pragma unroll
    for (int q = 0; q < 4; ++q) {
        e[q] = __expf(s[q] - m[q]);
        float v = e[q];
        #pragma unroll
        for (int off = 32; off >= 1; off >>= 1)
            v += __shfl_xor(v, off, 64);
        if ((t & 63) == 0) wsum[wv][q] = v;
    }
    __syncthreads();
    float a[4];
    #pragma unroll
    for (int q = 0; q < 4; ++q) {
        float S = wsum[0][q];
        #pragma unroll
        for (int i = 1; i < 16; ++i) S += wsum[i][q];
        a[q] = e[q] * (1.0f / S);
    }
    attn4_s[t] = make_float4(a[0], a[1], a[2], a[3]);
    #pragma unroll
    for (int q = 0; q < 4; ++q)
        outP[(b * Q_ + q0 + q) * C_ + t] = a[q];           // coalesced
    __syncthreads();

    // ---- phase 3: attn_output[q][h] = sum_c attn[q][c]*context[b][c][h]
    // 32 c-chunks of 32; two-step LDS reduction keeps red at 32 KiB.
    const float4* __restrict__ ctx4 = reinterpret_cast<const float4*>(context);
    const int hg   = t & 31;      // float4 h-chunk: h = hg*4..hg*4+3
    const int crep = t >> 5;      // 0..31
    const int cb   = crep * 32;
    float4 acc[4] = {{0,0,0,0},{0,0,0,0},{0,0,0,0},{0,0,0,0}};
    #pragma unroll 4
    for (int cc = 0; cc < 32; ++cc) {
        const int c = cb + cc;
        const float4 a4 = attn4_s[c];                      // LDS broadcast
        const float4 xv = ctx4[(b * C_ + c) * (H_ / 4) + hg];
        acc[0].x += a4.x * xv.x; acc[0].y += a4.x * xv.y; acc[0].z += a4.x * xv.z; acc[0].w += a4.x * xv.w;
        acc[1].x += a4.y * xv.x; acc[1].y += a4.y * xv.y; acc[1].z += a4.y * xv.z; acc[1].w += a4.y * xv.w;
        acc[2].x += a4.z * xv.x; acc[2].y += a4.z * xv.y; acc[2].z += a4.z * xv.z; acc[2].w += a4.z * xv.w;
        acc[3].x += a4.w * xv.x; acc[3].y += a4.w * xv.y; acc[3].z += a4.w * xv.z; acc[3].w += a4.w * xv.w;
    }
    float4* red4 = reinterpret_cast<float4*>(red);
    if (crep < 16) {
        #pragma unroll
        for (int q = 0; q < 4; ++q)
            red4[(crep * 4 + q) * 32 + hg] = acc[q];
    }
    __syncthreads();
    if (crep >= 16) {
        #pragma unroll
        for (int q = 0; q < 4; ++q) {
            const int idx = ((crep - 16) * 4 + q) * 32 + hg;
            float4 r = red4[idx];
            r.x += acc[q].x; r.y += acc[q].y; r.z += acc[q].z; r.w += acc[q].w;
            red4[idx] = r;
        }
    }
    __syncthreads();
    if (t < 512) {
        const int q = t >> 7, h = t & 127;
        float v = 0.f;
        #pragma unroll
        for (int cr = 0; cr < 16; ++cr)
            v += red[(cr * 4 + q) * H_ + h];
        outA[(b * Q_ + q0 + q) * H_ + h] = v;
    }
}

extern "C" void kernel_launch(void* const* d_in, const int* in_sizes, int n_in,
                              void* d_out, int out_size, void* d_ws, size_t ws_size,
                              hipStream_t stream) {
    const float* query   = (const float*)d_in[0];
    const float* context = (const float*)d_in[1];
    const float* Ww      = (const float*)d_in[2];
    const float* bw      = (const float*)d_in[3];
    const float* Ws      = (const float*)d_in[4];
    // d_in[5] (bs) unused: softmax-shift-invariant, outputs are post-softmax.

    float* outA = (float*)d_out;                 // attn_output: B*Q*H
    float* outP = outA + B_ * Q_ * H_;           // attn:        B*Q*C

    float* hq  = (float*)d_ws;                   // B*Q*H floats (512 KB)
    float* hc  = hq + B_ * Q_ * H_;              // B*C*H floats (2 MB)
    float* dcv = hc + B_ * C_ * H_;              // B*C floats   (16 KB)

    hipLaunchKernelGGL(proj_kernel, dim3(1280), dim3(128), 0, stream,
                       query, context, Ww, bw, Ws, hq, hc, dcv);
    hipLaunchKernelGGL(attn_kernel, dim3(256), dim3(1024), 0, stream,
                       hq, hc, Ws, dcv, context, outA, outP);
}

// Round 6
// 102.555 us; speedup vs baseline: 1.1851x; 1.0185x over previous
//
#include <hip/hip_runtime.h>

#define B_   4
#define Q_   256
#define C_   1024
#define H_   128
#define NEG  0.01f

// ---------------------------------------------------------------------------
// Kernel 1: hq[b,q,k] = sum_h query[b,q,h]*Ww[k,h]
//           hc[b,c,k] = sum_h context[b,c,h]*Ww[k,H+h] + bw[k]
// 4 rows per block, 128 threads (thread = output k) -> 1280 blocks,
// 2.5 waves/SIMD for latency hiding.
// Input rows are wave-uniform float4 loads; Ww row k is per-thread.
// [Empirically best variant: measured 101.96 us total in round 1.]
// ---------------------------------------------------------------------------
__global__ __launch_bounds__(128) void proj_kernel(
    const float* __restrict__ query, const float* __restrict__ context,
    const float* __restrict__ Ww, const float* __restrict__ bw,
    float* __restrict__ hq, float* __restrict__ hc)
{
    const int blk = blockIdx.x;
    const int k = threadIdx.x;
    const bool is_q = (blk < (B_ * Q_ / 4));              // 256 blocks for hq
    const int row0 = is_q ? (blk * 4) : ((blk - B_ * Q_ / 4) * 4);
    const float* __restrict__ in = is_q ? query : context;
    float* __restrict__ out = is_q ? hq : hc;

    const float4* __restrict__ Wrow =
        reinterpret_cast<const float4*>(Ww + k * (2 * H_) + (is_q ? 0 : H_));
    const float4* __restrict__ in4 =
        reinterpret_cast<const float4*>(in + row0 * H_);

    float acc[4] = {0.f, 0.f, 0.f, 0.f};
    #pragma unroll 4
    for (int h4 = 0; h4 < H_ / 4; ++h4) {
        const float4 w = Wrow[h4];
        #pragma unroll
        for (int r = 0; r < 4; ++r) {
            const float4 iv = in4[r * (H_ / 4) + h4];     // wave-uniform
            acc[r] += iv.x * w.x + iv.y * w.y + iv.z * w.z + iv.w * w.w;
        }
    }
    const float bias = is_q ? 0.f : bw[k];
    #pragma unroll
    for (int r = 0; r < 4; ++r)
        out[(row0 + r) * H_ + k] = acc[r] + bias;
}

// ---------------------------------------------------------------------------
// Kernel 2: per block = (b, 4 consecutive q). 512 threads (8 waves).
// b = blockIdx & 3 keeps each XCD pinned to one b (hc[b]+context[b] L2-local).
//
// Phase 1 uses the exact identity leaky(x) = 0.505x + 0.495|x|:
//   score[q,c] = 0.505*(Dq[q] + dc[c]) + 0.495*sum_k Ws[k]*|hq+hc|
// Dq from an LDS-staged hq (once per block), dc fused in the k-loop.
// Inner loop: 2 VALU ops/element (v_add + v_fma with free abs modifier),
// wave-uniform operands from LDS; thread owns c in {t, t+512} -> two
// independent load streams per thread (ILP), per-lane 16B row walk (L1-hot).
// bs omitted: softmax is shift-invariant, both outputs are post-softmax.
// ---------------------------------------------------------------------------
__global__ __launch_bounds__(512) void attn_kernel(
    const float* __restrict__ hq, const float* __restrict__ hc,
    const float* __restrict__ Ws, const float* __restrict__ context,
    float* __restrict__ outA, float* __restrict__ outP)
{
    const int b  = blockIdx.x & 3;           // XCD-aligned b mapping
    const int q0 = (blockIdx.x >> 2) * 4;    // 64 q-groups per b
    const int t  = threadIdx.x;
    const int wv = t >> 6;                   // wave id 0..7

    __shared__ float4 attn4_s[C_];           // 16 KiB: attn packed {q0..q3} per c
    __shared__ float  red[16 * 4 * H_];      // 32 KiB: phase-3 partials
    __shared__ float  s_hq[4][H_];           // 2 KiB: this block's 4 hq rows
    __shared__ float  s_ws[H_];              // 0.5 KiB
    __shared__ float  wred[8][4];
    __shared__ float  wsum[8][4];
    __shared__ float  dqp[2][4];

    // ---- stage hq rows + Ws into LDS
    {
        const int q = t >> 7, k = t & 127;
        s_hq[q][k] = hq[(b * Q_ + q0 + q) * H_ + k];
        if (t < H_) s_ws[t] = Ws[t];
    }
    __syncthreads();

    // ---- Dq[q] = dot(Ws, hq_row_q)  (2 waves, shuffle butterflies)
    if (t < 128) {
        float v[4];
        #pragma unroll
        for (int q = 0; q < 4; ++q) v[q] = s_ws[t] * s_hq[q][t];
        #pragma unroll
        for (int off = 32; off >= 1; off >>= 1) {
            #pragma unroll
            for (int q = 0; q < 4; ++q) v[q] += __shfl_xor(v[q], off, 64);
        }
        if ((t & 63) == 0) {
            #pragma unroll
            for (int q = 0; q < 4; ++q) dqp[t >> 6][q] = v[q];
        }
    }
    __syncthreads();
    float Dq[4];
    #pragma unroll
    for (int q = 0; q < 4; ++q) Dq[q] = dqp[0][q] + dqp[1][q];

    // ---- phase 1: abs-part + dc over c in {t, t+512}
    const int c0 = t, c1 = t + 512;
    const float4* __restrict__ ws4 = reinterpret_cast<const float4*>(s_ws);
    const float4* __restrict__ hcp0 =
        reinterpret_cast<const float4*>(hc + (b * C_ + c0) * H_);
    const float4* __restrict__ hcp1 =
        reinterpret_cast<const float4*>(hc + (b * C_ + c1) * H_);

    float sabs[4][2] = {{0.f,0.f},{0.f,0.f},{0.f,0.f},{0.f,0.f}};
    float dc0 = 0.f, dc1 = 0.f;
    #pragma unroll 4
    for (int k0 = 0; k0 < H_ / 4; ++k0) {
        const float4 wsv = ws4[k0];                        // LDS broadcast
        float4 hqv[4];
        #pragma unroll
        for (int q = 0; q < 4; ++q)
            hqv[q] = reinterpret_cast<const float4*>(s_hq[q])[k0];  // LDS broadcast
        const float4 h0 = hcp0[k0];
        const float4 h1 = hcp1[k0];
        dc0 += wsv.x * h0.x + wsv.y * h0.y + wsv.z * h0.z + wsv.w * h0.w;
        dc1 += wsv.x * h1.x + wsv.y * h1.y + wsv.z * h1.z + wsv.w * h1.w;
        #pragma unroll
        for (int q = 0; q < 4; ++q) {
            sabs[q][0] += wsv.x * fabsf(hqv[q].x + h0.x)
                        + wsv.y * fabsf(hqv[q].y + h0.y)
                        + wsv.z * fabsf(hqv[q].z + h0.z)
                        + wsv.w * fabsf(hqv[q].w + h0.w);
            sabs[q][1] += wsv.x * fabsf(hqv[q].x + h1.x)
                        + wsv.y * fabsf(hqv[q].y + h1.y)
                        + wsv.z * fabsf(hqv[q].z + h1.z)
                        + wsv.w * fabsf(hqv[q].w + h1.w);
        }
    }
    float s[4][2];
    #pragma unroll
    for (int q = 0; q < 4; ++q) {
        s[q][0] = 0.505f * (Dq[q] + dc0) + 0.495f * sabs[q][0];
        s[q][1] = 0.505f * (Dq[q] + dc1) + 0.495f * sabs[q][1];
    }

    // ---- phase 2: softmax over the 1024 c per q row
    float m[4];
    #pragma unroll
    for (int q = 0; q < 4; ++q) {
        float v = fmaxf(s[q][0], s[q][1]);
        #pragma unroll
        for (int off = 32; off >= 1; off >>= 1)
            v = fmaxf(v, __shfl_xor(v, off, 64));
        m[q] = v;
    }
    if ((t & 63) == 0) {
        #pragma unroll
        for (int q = 0; q < 4; ++q) wred[wv][q] = m[q];
    }
    __syncthreads();
    #pragma unroll
    for (int q = 0; q < 4; ++q) {
        float v = wred[0][q];
        #pragma unroll
        for (int i = 1; i < 8; ++i) v = fmaxf(v, wred[i][q]);
        m[q] = v;
    }
    float e[4][2], p[4];
    #pragma unroll
    for (int q = 0; q < 4; ++q) {
        e[q][0] = __expf(s[q][0] - m[q]);
        e[q][1] = __expf(s[q][1] - m[q]);
        float v = e[q][0] + e[q][1];
        #pragma unroll
        for (int off = 32; off >= 1; off >>= 1)
            v += __shfl_xor(v, off, 64);
        p[q] = v;
    }
    if ((t & 63) == 0) {
        #pragma unroll
        for (int q = 0; q < 4; ++q) wsum[wv][q] = p[q];
    }
    __syncthreads();
    float rS[4];
    #pragma unroll
    for (int q = 0; q < 4; ++q) {
        float S = wsum[0][q];
        #pragma unroll
        for (int i = 1; i < 8; ++i) S += wsum[i][q];
        rS[q] = 1.0f / S;
    }
    float a0[4], a1[4];
    #pragma unroll
    for (int q = 0; q < 4; ++q) {
        a0[q] = e[q][0] * rS[q];
        a1[q] = e[q][1] * rS[q];
    }
    attn4_s[c0] = make_float4(a0[0], a0[1], a0[2], a0[3]);
    attn4_s[c1] = make_float4(a1[0], a1[1], a1[2], a1[3]);
    #pragma unroll
    for (int q = 0; q < 4; ++q) {
        outP[(b * Q_ + q0 + q) * C_ + c0] = a0[q];
        outP[(b * Q_ + q0 + q) * C_ + c1] = a1[q];
    }
    __syncthreads();

    // ---- phase 3: attn_output[q][h] = sum_c attn[q][c]*context[b][c][h]
    const float4* __restrict__ ctx4 = reinterpret_cast<const float4*>(context);
    const int hg   = t & 31;      // float4 h-chunk: h = hg*4..hg*4+3
    const int crep = t >> 5;      // 16 c-chunks of 64
    float4 acc[4] = {{0,0,0,0},{0,0,0,0},{0,0,0,0},{0,0,0,0}};
    const int cb = crep * 64;
    #pragma unroll 4
    for (int cc = 0; cc < 64; ++cc) {
        const int c = cb + cc;
        const float4 a4 = attn4_s[c];
        const float4 xv = ctx4[(b * C_ + c) * (H_ / 4) + hg];
        acc[0].x += a4.x * xv.x; acc[0].y += a4.x * xv.y; acc[0].z += a4.x * xv.z; acc[0].w += a4.x * xv.w;
        acc[1].x += a4.y * xv.x; acc[1].y += a4.y * xv.y; acc[1].z += a4.y * xv.z; acc[1].w += a4.y * xv.w;
        acc[2].x += a4.z * xv.x; acc[2].y += a4.z * xv.y; acc[2].z += a4.z * xv.z; acc[2].w += a4.z * xv.w;
        acc[3].x += a4.w * xv.x; acc[3].y += a4.w * xv.y; acc[3].z += a4.w * xv.z; acc[3].w += a4.w * xv.w;
    }
    float4* red4 = reinterpret_cast<float4*>(red);
    #pragma unroll
    for (int q = 0; q < 4; ++q)
        red4[(crep * 4 + q) * 32 + hg] = acc[q];
    __syncthreads();
    {
        const int q = t >> 7, h = t & 127;
        float v = 0.f;
        #pragma unroll
        for (int cr = 0; cr < 16; ++cr)
            v += red[(cr * 4 + q) * H_ + h];
        outA[(b * Q_ + q0 + q) * H_ + h] = v;
    }
}

extern "C" void kernel_launch(void* const* d_in, const int* in_sizes, int n_in,
                              void* d_out, int out_size, void* d_ws, size_t ws_size,
                              hipStream_t stream) {
    const float* query   = (const float*)d_in[0];
    const float* context = (const float*)d_in[1];
    const float* Ww      = (const float*)d_in[2];
    const float* bw      = (const float*)d_in[3];
    const float* Ws      = (const float*)d_in[4];
    // d_in[5] (bs) intentionally unused: softmax is shift-invariant and both
    // outputs are post-softmax quantities.

    float* outA = (float*)d_out;                 // attn_output: B*Q*H
    float* outP = outA + B_ * Q_ * H_;           // attn:        B*Q*C

    float* hq = (float*)d_ws;                    // B*Q*H floats (512 KB)
    float* hc = hq + B_ * Q_ * H_;               // B*C*H floats (2 MB)

    hipLaunchKernelGGL(proj_kernel, dim3(1280), dim3(128), 0, stream,
                       query, context, Ww, bw, hq, hc);
    hipLaunchKernelGGL(attn_kernel, dim3(256), dim3(512), 0, stream,
                       hq, hc, Ws, context, outA, outP);
}